// Round 8
// baseline (50.238 us; speedup 1.0000x reference)
//
#include <hip/hip_runtime.h>

// out[b,o] = max_i min(m[b,i], clamp(w[i,o],0,1)); B=128, I=2048, O=512, fp32.
//
// VALU-bound formulation, minimal VMEM instruction count:
//   grid = 512 blocks = [ig 32][ob 2][bb 8]; block = 512 thr = 8 waves.
//   wave -> 2 b-rows; lane -> 4 o-cols (float4 W loads, 1 KiB/wave/instr).
//   i-group = 64. Per thread: 96 VMEM, 1024 VALU, 8 atomics.
//   Clamp is free: acc init 0 absorbs w<0 (min(m,w)<0 loses the max) and
//   m<1 absorbs w>1. Cross-i-group reduce: atomicMax on int bit patterns
//   (all results >= 0 -> order-isomorphic; replay-idempotent; 0xAA poison is
//   a negative int -> overwritten on first replay). No LDS, no barriers.
//   __launch_bounds__(512,4): 4 waves/SIMD (16/CU), VGPR capped at 128.

#define UPD(acc, mv, wv)                          \
    acc.x = fmaxf(acc.x, fminf(mv, wv.x));        \
    acc.y = fmaxf(acc.y, fminf(mv, wv.y));        \
    acc.z = fmaxf(acc.z, fminf(mv, wv.z));        \
    acc.w = fmaxf(acc.w, fminf(mv, wv.w));

__global__ __launch_bounds__(512, 4)
void tmm(const float* __restrict__ M, const float* __restrict__ W,
         float* __restrict__ out) {
    const int t  = threadIdx.x;
    const int wv = t >> 6, l = t & 63;
    const int bid = blockIdx.x;            // [ig 32][ob 2][bb 8]
    const int bb = bid & 7;                // fastest -> XCD locality on b-strip
    const int ob = (bid >> 3) & 1;
    const int ig = bid >> 4;
    const int r0 = bb * 16 + wv * 2;       // 2 rows per wave
    const int c0 = ob * 256 + l * 4;       // 4 cols per lane
    const int i0 = ig * 64;                // 64 i per block

    const float* Wp = W + (size_t)i0 * 512 + c0;
    const float* M0 = M + (size_t)r0 * 2048 + i0;
    const float* M1 = M0 + 2048;

    float4 a0 = make_float4(0.f, 0.f, 0.f, 0.f);
    float4 a1 = make_float4(0.f, 0.f, 0.f, 0.f);

#pragma unroll 4
    for (int i4 = 0; i4 < 16; ++i4) {
        float4 m0 = *(const float4*)&M0[i4 * 4];     // uniform -> broadcast
        float4 m1 = *(const float4*)&M1[i4 * 4];
        float4 w0 = *(const float4*)&Wp[(i4 * 4 + 0) * 512];  // 1 KiB/wave
        float4 w1 = *(const float4*)&Wp[(i4 * 4 + 1) * 512];
        float4 w2 = *(const float4*)&Wp[(i4 * 4 + 2) * 512];
        float4 w3 = *(const float4*)&Wp[(i4 * 4 + 3) * 512];
        UPD(a0, m0.x, w0)  UPD(a0, m0.y, w1)  UPD(a0, m0.z, w2)  UPD(a0, m0.w, w3)
        UPD(a1, m1.x, w0)  UPD(a1, m1.y, w1)  UPD(a1, m1.z, w2)  UPD(a1, m1.w, w3)
    }

    int* o0 = (int*)out + r0 * 512 + c0;
    int* o1 = o0 + 512;
    atomicMax(o0,     __float_as_int(a0.x));
    atomicMax(o0 + 1, __float_as_int(a0.y));
    atomicMax(o0 + 2, __float_as_int(a0.z));
    atomicMax(o0 + 3, __float_as_int(a0.w));
    atomicMax(o1,     __float_as_int(a1.x));
    atomicMax(o1 + 1, __float_as_int(a1.y));
    atomicMax(o1 + 2, __float_as_int(a1.z));
    atomicMax(o1 + 3, __float_as_int(a1.w));
}

extern "C" void kernel_launch(void* const* d_in, const int* in_sizes, int n_in,
                              void* d_out, int out_size, void* d_ws, size_t ws_size,
                              hipStream_t stream) {
    const float* M = (const float*)d_in[0];   // [128][2048]
    const float* W = (const float*)d_in[1];   // [2048][512]
    float* out = (float*)d_out;               // [128][512]
    tmm<<<dim3(512), dim3(512), 0, stream>>>(M, W, out);
}

// Round 9
// 26.029 us; speedup vs baseline: 1.9301x; 1.9301x over previous
//
#include <hip/hip_runtime.h>

// out[b,o] = max_i min(m[b,i], clamp(w[i,o],0,1)); B=128, I=2048, O=512, fp32.
//
// Single kernel, K=1 (each output owned by one block), NO atomics (R8 showed
// 2M cross-XCD atomicMax -> 66 MB HBM write-through, 1.8 TB/s bound).
//   grid = 256 blocks = [bt 32 (4 b-rows)][ot 8 (64 o-cols)]; ot = bid&7 so
//   XCD x always sees o-strip x -> its 512 KB W strip stays L2-resident.
//   block = 512 thr = 8 waves (2/SIMD); wave = i-slice of 256 (slice == wave
//   id -> M addresses wave-uniform -> 1-line broadcast loads); lane = o-col
//   (W dword loads, 256 B/wave/instr, each W element read once per block).
//   Per 4-i step: 8 VMEM (4 M-float4 + 4 W-dword) vs 64 VALU -> VALU-bound.
//   Clamp free: acc init 0 absorbs w<0; m<1 absorbs w>1. Pure fp32, absmax 0.
//   Epilogue: 8-slice LDS fan-in (8 KB, conflict-free), plain stores.

__global__ __launch_bounds__(512)
void tmm(const float* __restrict__ M, const float* __restrict__ W,
         float* __restrict__ out) {
    __shared__ float part[8][4][64];       // 8 KB
    const int t = threadIdx.x;
    const int c = t & 63;                  // o-col within tile
    const int s = t >> 6;                  // i-slice == wave id
    const int bid = blockIdx.x;
    const int ot = bid & 7, bt = bid >> 3; // ot fastest -> pinned per XCD
    const int b0 = bt * 4, o0 = ot * 64;

    const float* Wp = W + (size_t)(s * 256) * 512 + o0 + c;
    const float* Mp = M + (size_t)b0 * 2048 + s * 256;

    float a0 = 0.f, a1 = 0.f, a2 = 0.f, a3 = 0.f;

#pragma unroll 2
    for (int st = 0; st < 64; ++st) {
        float4 m0 = *(const float4*)&Mp[st * 4];          // uniform -> broadcast
        float4 m1 = *(const float4*)&Mp[2048 + st * 4];
        float4 m2 = *(const float4*)&Mp[4096 + st * 4];
        float4 m3 = *(const float4*)&Mp[6144 + st * 4];
        float w0 = Wp[(st * 4 + 0) * 512];                // 256 B / wave instr
        float w1 = Wp[(st * 4 + 1) * 512];
        float w2 = Wp[(st * 4 + 2) * 512];
        float w3 = Wp[(st * 4 + 3) * 512];
        a0 = fmaxf(a0, fminf(m0.x, w0)); a1 = fmaxf(a1, fminf(m1.x, w0));
        a2 = fmaxf(a2, fminf(m2.x, w0)); a3 = fmaxf(a3, fminf(m3.x, w0));
        a0 = fmaxf(a0, fminf(m0.y, w1)); a1 = fmaxf(a1, fminf(m1.y, w1));
        a2 = fmaxf(a2, fminf(m2.y, w1)); a3 = fmaxf(a3, fminf(m3.y, w1));
        a0 = fmaxf(a0, fminf(m0.z, w2)); a1 = fmaxf(a1, fminf(m1.z, w2));
        a2 = fmaxf(a2, fminf(m2.z, w2)); a3 = fmaxf(a3, fminf(m3.z, w2));
        a0 = fmaxf(a0, fminf(m0.w, w3)); a1 = fmaxf(a1, fminf(m1.w, w3));
        a2 = fmaxf(a2, fminf(m2.w, w3)); a3 = fmaxf(a3, fminf(m3.w, w3));
    }

    // slice partials -> LDS (lanes hit distinct banks per row: addr = c)
    part[s][0][c] = a0;
    part[s][1][c] = a1;
    part[s][2][c] = a2;
    part[s][3][c] = a3;
    __syncthreads();

    if (t < 256) {                         // one output per thread
        const int r = t >> 6, cc = t & 63;
        float v = part[0][r][cc];
#pragma unroll
        for (int ss = 1; ss < 8; ++ss) v = fmaxf(v, part[ss][r][cc]);
        out[(b0 + r) * 512 + o0 + cc] = v; // plain coalesced store, once per elem
    }
}

extern "C" void kernel_launch(void* const* d_in, const int* in_sizes, int n_in,
                              void* d_out, int out_size, void* d_ws, size_t ws_size,
                              hipStream_t stream) {
    const float* M = (const float*)d_in[0];   // [128][2048]
    const float* W = (const float*)d_in[1];   // [2048][512]
    float* out = (float*)d_out;               // [128][512]
    tmm<<<dim3(256), dim3(512), 0, stream>>>(M, W, out);
}